// Round 17
// baseline (1044.465 us; speedup 1.0000x reference)
//
#include <hip/hip_runtime.h>

#define NTOK 49
#define CDIM 384
#define HEADS 12
#define HD 32
#define NWIN 64
#define NQKV 1152
#define SCALE 0.17677669529663687f  // 32^-0.5

typedef __attribute__((ext_vector_type(8))) __bf16 bf16x8;
typedef __attribute__((ext_vector_type(4))) float f32x4;

// workspace offsets (bytes), all 256-aligned
#define OFF_WQKVT   0ull                 // 1152*384 bf16 = 884736
#define OFF_WOUTT   884736ull            // 384*384 bf16  = 294912
#define OFF_RPBF    1179648ull           // 12*4*4*64*4 f32 = 196608
#define OFF_MASKF   1376256ull           // 64*4*4*64*4 f32 = 1048576
#define OFF_QKVB    8555520ull           // 3 tensors [B][12][49][32] bf16 = 462422016 total
#define OFF_ATTNOUT 470977536ull         // 200704*384 bf16 = 154140672
#define OFF_XB      OFF_ATTNOUT          // xb aliases attnout: xb dead before attn writes
// total ~625.1 MB

#define TSIZE 77070336ull                // per-tensor elems: 200704*384 = B*HEADS*NTOK*HD

__device__ __forceinline__ void async_copy16(__bf16* lds_dst, const __bf16* g_src) {
    __builtin_amdgcn_global_load_lds(
        (const __attribute__((address_space(1))) void*)g_src,
        (__attribute__((address_space(3))) void*)lds_dst,
        16, 0, 0);
}

// ---------------- prep kernels ----------------

__global__ void prep_weights(const float* __restrict__ Wqkv, const float* __restrict__ Wout,
                             __bf16* __restrict__ WqkvT, __bf16* __restrict__ WoutT) {
    int idx = blockIdx.x * 256 + threadIdx.x;
    if (idx < NQKV * CDIM) {
        int n = idx / CDIM, k = idx % CDIM;
        WqkvT[idx] = (__bf16)Wqkv[(size_t)k * NQKV + n];
    }
    if (idx < CDIM * CDIM) {
        int n = idx / CDIM, k = idx % CDIM;
        WoutT[idx] = (__bf16)Wout[(size_t)k * CDIM + n];
    }
}

// fragment-layout bias tables: rpbF[h][mt][nt][lane][r], maskF[w][mt][nt][lane][r]
__global__ void prep_frag(const float* __restrict__ rpb, const int* __restrict__ rel,
                          const float* __restrict__ mask,
                          float* __restrict__ rpbF, float* __restrict__ maskF) {
    int idx = blockIdx.x * 256 + threadIdx.x;
    if (idx < 49152) {
        int r = idx & 3, lane = (idx >> 2) & 63, nt = (idx >> 8) & 3, mt = (idx >> 10) & 3, h = idx >> 12;
        int m = mt * 16 + ((lane >> 4) << 2) + r, n = nt * 16 + (lane & 15);
        rpbF[idx] = (m < NTOK && n < NTOK) ? rpb[rel[m * NTOK + n] * HEADS + h] : 0.f;
    } else {
        int i2 = idx - 49152;
        if (i2 < 262144) {
            int r = i2 & 3, lane = (i2 >> 2) & 63, nt = (i2 >> 8) & 3, mt = (i2 >> 10) & 3, w = i2 >> 12;
            int m = mt * 16 + ((lane >> 4) << 2) + r, n = nt * 16 + (lane & 15);
            maskF[i2] = (m < NTOK && n < NTOK) ? mask[(size_t)w * NTOK * NTOK + m * NTOK + n] : 0.f;
        }
    }
}

// x fp32 -> bf16, streaming (8 elems / thread / iter)
__global__ __launch_bounds__(256) void prep_xb(const float* __restrict__ x,
                                               __bf16* __restrict__ xb, int total8) {
    int stride = gridDim.x * 256;
    for (int i = blockIdx.x * 256 + threadIdx.x; i < total8; i += stride) {
        float4 a = reinterpret_cast<const float4*>(x)[i * 2];
        float4 b = reinterpret_cast<const float4*>(x)[i * 2 + 1];
        union { __bf16 h[8]; uint4 u; } t;
        t.h[0] = (__bf16)a.x; t.h[1] = (__bf16)a.y; t.h[2] = (__bf16)a.z; t.h[3] = (__bf16)a.w;
        t.h[4] = (__bf16)b.x; t.h[5] = (__bf16)b.y; t.h[6] = (__bf16)b.z; t.h[7] = (__bf16)b.w;
        reinterpret_cast<uint4*>(xb)[i] = t.u;
    }
}

// ---------------- K1: qkv GEMM — 2-phase pipelined (issue-next, compute-current, barrier) ----------------
// BK=32 double-buffered: buf p at smem[p*8192], A chunks [0,4096), B chunks [4096,8192).
// Per iter: issue 4 async chunks for t+1, 8 ds_read + 16 MFMA on t, one __syncthreads
// (its vmcnt(0) drains the t+1 loads AFTER compute -> latency hidden).

__global__ __launch_bounds__(256, 4) void gemm_qkv(
    const __bf16* __restrict__ xb, const __bf16* __restrict__ WqkvT,
    const float* __restrict__ bqkv, __bf16* __restrict__ qkvb)
{
    __shared__ __attribute__((aligned(16))) __bf16 smem[16384];  // 2 x (A 4096 + B 4096); C overlays

    // bijective XCD-chunk swizzle: nwg = 14112 = 8 * 1764
    const int cpx  = 14112 >> 3;                     // 1764
    const int lid  = (blockIdx.x & 7) * cpx + (blockIdx.x >> 3);
    const int mblk = lid / 9, nblk = lid % 9;
    const int n0  = nblk * 128;
    const int bm0 = mblk * 128;

    const int tid = threadIdx.x;
    const int wave = tid >> 6, lane = tid & 63;
    const int l15 = lane & 15, l4 = lane >> 4;
    const int wr = wave >> 1, wc = wave & 1;

    // per-wave staging sources (chunk c = wave*4+j): c<8 -> A m-subtile c, else B n-subtile c-8
    auto stage = [&](int p, int k0) {
#pragma unroll
        for (int j = 0; j < 4; ++j) {
            int c = wave * 4 + j;
            if (c < 8) {
                const __bf16* sa = xb + (size_t)(bm0 + c * 16 + l15) * CDIM + k0 + l4 * 8;
                async_copy16(&smem[p * 8192 + c * 512], sa);
            } else {
                const __bf16* sb = WqkvT + (size_t)(n0 + (c - 8) * 16 + l15) * CDIM + k0 + l4 * 8;
                async_copy16(&smem[p * 8192 + 4096 + (c - 8) * 512], sb);
            }
        }
    };

    f32x4 acc[4][4] = {};

    stage(0, 0);
    __syncthreads();   // prologue drain (exposed once)

    for (int t = 0; t < 12; ++t) {
        if (t < 11) stage((t + 1) & 1, (t + 1) * 32);
        const int p = t & 1;
        bf16x8 af[4], bf[4];
#pragma unroll
        for (int mi = 0; mi < 4; ++mi)
            af[mi] = *reinterpret_cast<const bf16x8*>(&smem[p * 8192 + (wr * 4 + mi) * 512 + lane * 8]);
#pragma unroll
        for (int ni = 0; ni < 4; ++ni)
            bf[ni] = *reinterpret_cast<const bf16x8*>(&smem[p * 8192 + 4096 + (wc * 4 + ni) * 512 + lane * 8]);
#pragma unroll
        for (int mi = 0; mi < 4; ++mi)
#pragma unroll
            for (int ni = 0; ni < 4; ++ni)
                acc[mi][ni] = __builtin_amdgcn_mfma_f32_16x16x32_bf16(af[mi], bf[ni], acc[mi][ni], 0, 0, 0);
        __syncthreads();   // drains t+1 loads (hidden under this iter's MFMAs) + read-done barrier
    }

    const float scl = (n0 < CDIM) ? SCALE : 1.0f;
    float bias[4];
#pragma unroll
    for (int ni = 0; ni < 4; ++ni)
        bias[ni] = bqkv[n0 + wc * 64 + ni * 16 + l15];

    __bf16* Cs = smem;   // [128][128] bf16, byte ^= ((row>>2)&3)<<5
#pragma unroll
    for (int mi = 0; mi < 4; ++mi)
#pragma unroll
        for (int ni = 0; ni < 4; ++ni)
#pragma unroll
            for (int r = 0; r < 4; ++r) {
                int row = wr * 64 + mi * 16 + l4 * 4 + r;
                int col = wc * 64 + ni * 16 + l15;
                int byte = (row * 256 + col * 2) ^ (((row >> 2) & 3) << 5);
                *reinterpret_cast<__bf16*>(reinterpret_cast<char*>(Cs) + byte) =
                    (__bf16)((acc[mi][ni][r] + bias[ni]) * scl);
            }
    __syncthreads();

    // head-blocked scatter: tensor = n0/384; 128 cols = 4 heads h0..h0+3
    const int which = n0 / CDIM;
    const int h0    = (n0 % CDIM) >> 5;
    __bf16* tbase = qkvb + (size_t)which * TSIZE;
#pragma unroll
    for (int it = 0; it < 8; ++it) {
        int idx = it * 4096 + tid * 16;
        int row = idx >> 8, bcol = idx & 255;
        int sb = (row * 256 + bcol) ^ (((row >> 2) & 3) << 5);
        uint4 v = *reinterpret_cast<const uint4*>(reinterpret_cast<const char*>(Cs) + sb);
        int grow = bm0 + row;
        int b = grow / NTOK, tok = grow - b * NTOK;
        int col = bcol >> 1;                 // 0..127
        int h = h0 + (col >> 5), d = col & 31;
        *reinterpret_cast<uint4*>(&tbase[(((size_t)b * HEADS + h) * NTOK + tok) * HD + d]) = v;
    }
}

// ---------------- K2: attention (unchanged from r16) ----------------

__global__ __launch_bounds__(256) void attn(
    const __bf16* __restrict__ qkvb, const float* __restrict__ rpbF,
    const float* __restrict__ maskF, __bf16* __restrict__ attnout)
{
    __shared__ __attribute__((aligned(16))) __bf16 ps[4][2][64][8];   // [wave][kb][lane][8]
    __shared__ __attribute__((aligned(16))) __bf16 ot[64 * 136];      // [tok][head-col], stride 136
    const int b = blockIdx.x;
    const int tid = threadIdx.x;
    const int wave = tid >> 6, lane = tid & 63;
    const int l15 = lane & 15, l4 = lane >> 4;
    const int h = blockIdx.y * 4 + wave;
    const int w = b & (NWIN - 1);

    const size_t hoff = (((size_t)b * HEADS + h) * NTOK) * HD;
    const __bf16* qb = qkvb + hoff;
    const __bf16* kb = qkvb + TSIZE + hoff;
    const __bf16* vb = qkvb + 2 * TSIZE + hoff;
    const f32x4* rpbF4  = reinterpret_cast<const f32x4*>(rpbF);
    const f32x4* maskF4 = reinterpret_cast<const f32x4*>(maskF);

    // vT B-frags via register gather
    bf16x8 vf[2][2];
#pragma unroll
    for (int dt = 0; dt < 2; ++dt)
#pragma unroll
        for (int kb2 = 0; kb2 < 2; ++kb2)
#pragma unroll
            for (int j = 0; j < 8; ++j) {
                int tok = kb2 * 32 + l4 * 8 + j;
                vf[dt][kb2][j] = vb[(size_t)tok * HD + dt * 16 + l15];
            }

    bf16x8 kf[4];
#pragma unroll
    for (int nt = 0; nt < 4; ++nt)
        kf[nt] = *reinterpret_cast<const bf16x8*>(kb + (size_t)(nt * 16 + l15) * HD + l4 * 8);

    for (int mt = 0; mt < 4; ++mt) {
        bf16x8 qf = *reinterpret_cast<const bf16x8*>(qb + (size_t)(mt * 16 + l15) * HD + l4 * 8);

        f32x4 rb[4], mb[4];
#pragma unroll
        for (int nt = 0; nt < 4; ++nt) {
            rb[nt] = rpbF4[((h * 4 + mt) * 4 + nt) * 64 + lane];
            mb[nt] = maskF4[((w * 4 + mt) * 4 + nt) * 64 + lane];
        }

        f32x4 s[4];
#pragma unroll
        for (int nt = 0; nt < 4; ++nt) {
            f32x4 z = {};
            s[nt] = __builtin_amdgcn_mfma_f32_16x16x32_bf16(qf, kf[nt], z, 0, 0, 0);
        }

#pragma unroll
        for (int r = 0; r < 4; ++r) {
            float vals[4];
#pragma unroll
            for (int nt = 0; nt < 4; ++nt) {
                int n = nt * 16 + l15;
                vals[nt] = (n < NTOK) ? (s[nt][r] + rb[nt][r] + mb[nt][r]) : -1e30f;
            }
            float mx = fmaxf(fmaxf(vals[0], vals[1]), fmaxf(vals[2], vals[3]));
            mx = fmaxf(mx, __shfl_xor(mx, 1));
            mx = fmaxf(mx, __shfl_xor(mx, 2));
            mx = fmaxf(mx, __shfl_xor(mx, 4));
            mx = fmaxf(mx, __shfl_xor(mx, 8));
            float e0 = __expf(vals[0] - mx);
            float e1 = __expf(vals[1] - mx);
            float e2 = __expf(vals[2] - mx);
            float e3 = __expf(vals[3] - mx);
            float sum = (e0 + e1) + (e2 + e3);
            sum += __shfl_xor(sum, 1);
            sum += __shfl_xor(sum, 2);
            sum += __shfl_xor(sum, 4);
            sum += __shfl_xor(sum, 8);
            float inv = 1.0f / sum;
            float ev[4] = {e0, e1, e2, e3};
#pragma unroll
            for (int nt = 0; nt < 4; ++nt) {
                int lp = (l4 * 4 + r) + 16 * ((nt & 1) * 2 + (l15 >> 3));
                ps[wave][nt >> 1][lp][l15 & 7] = (__bf16)(ev[nt] * inv);
            }
        }

        f32x4 o[2] = {};
#pragma unroll
        for (int kb2 = 0; kb2 < 2; ++kb2) {
            bf16x8 ap = *reinterpret_cast<const bf16x8*>(&ps[wave][kb2][lane][0]);
#pragma unroll
            for (int dt = 0; dt < 2; ++dt)
                o[dt] = __builtin_amdgcn_mfma_f32_16x16x32_bf16(ap, vf[dt][kb2], o[dt], 0, 0, 0);
        }
#pragma unroll
        for (int dt = 0; dt < 2; ++dt)
#pragma unroll
            for (int r = 0; r < 4; ++r) {
                int tok = mt * 16 + l4 * 4 + r;
                ot[tok * 136 + wave * 32 + dt * 16 + l15] = (__bf16)o[dt][r];
            }
    }
    __syncthreads();

    // cooperative coalesced write: [49 rows][128 cols] -> attnout cols gy*128..+127
#pragma unroll
    for (int it = 0; it < 4; ++it) {
        int e = it * 2048 + tid * 8;
        int row = e >> 7, c2 = e & 127;
        if (row < NTOK) {
            uint4 v = *reinterpret_cast<const uint4*>(&ot[row * 136 + c2]);
            *reinterpret_cast<uint4*>(
                &attnout[((size_t)b * NTOK + row) * CDIM + blockIdx.y * 128 + c2]) = v;
        }
    }
}

// ---------------- K3: out projection — same 2-phase pipelined template ----------------

__global__ __launch_bounds__(256, 4) void out_proj(
    const __bf16* __restrict__ A, const __bf16* __restrict__ WoutT,
    const float* __restrict__ bout, float* __restrict__ out)
{
    __shared__ __attribute__((aligned(16))) __bf16 smem[16384];  // 2 x (A 4096 + B 4096)

    // bijective XCD-chunk swizzle: nwg = 4704 = 8 * 588; n-fastest for A-tile L2 reuse
    const int cpx  = 4704 >> 3;                      // 588
    const int lid  = (blockIdx.x & 7) * cpx + (blockIdx.x >> 3);
    const int mblk = lid / 3, nblk = lid % 3;
    const int n0  = nblk * 128;
    const int bm0 = mblk * 128;

    const int tid = threadIdx.x;
    const int wave = tid >> 6, lane = tid & 63;
    const int l15 = lane & 15, l4 = lane >> 4;
    const int wr = wave >> 1, wc = wave & 1;

    auto stage = [&](int p, int k0) {
#pragma unroll
        for (int j = 0; j < 4; ++j) {
            int c = wave * 4 + j;
            if (c < 8) {
                const __bf16* sa = A + (size_t)(bm0 + c * 16 + l15) * CDIM + k0 + l4 * 8;
                async_copy16(&smem[p * 8192 + c * 512], sa);
            } else {
                const __bf16* sb = WoutT + (size_t)(n0 + (c - 8) * 16 + l15) * CDIM + k0 + l4 * 8;
                async_copy16(&smem[p * 8192 + 4096 + (c - 8) * 512], sb);
            }
        }
    };

    f32x4 acc[4][4] = {};

    stage(0, 0);
    __syncthreads();

    for (int t = 0; t < 12; ++t) {
        if (t < 11) stage((t + 1) & 1, (t + 1) * 32);
        const int p = t & 1;
        bf16x8 af[4], bf[4];
#pragma unroll
        for (int mi = 0; mi < 4; ++mi)
            af[mi] = *reinterpret_cast<const bf16x8*>(&smem[p * 8192 + (wr * 4 + mi) * 512 + lane * 8]);
#pragma unroll
        for (int ni = 0; ni < 4; ++ni)
            bf[ni] = *reinterpret_cast<const bf16x8*>(&smem[p * 8192 + 4096 + (wc * 4 + ni) * 512 + lane * 8]);
#pragma unroll
        for (int mi = 0; mi < 4; ++mi)
#pragma unroll
            for (int ni = 0; ni < 4; ++ni)
                acc[mi][ni] = __builtin_amdgcn_mfma_f32_16x16x32_bf16(af[mi], bf[ni], acc[mi][ni], 0, 0, 0);
        __syncthreads();
    }

    float bias[4];
#pragma unroll
    for (int ni = 0; ni < 4; ++ni)
        bias[ni] = bout[n0 + wc * 64 + ni * 16 + l15];

#pragma unroll
    for (int mi = 0; mi < 4; ++mi)
#pragma unroll
        for (int ni = 0; ni < 4; ++ni)
#pragma unroll
            for (int r = 0; r < 4; ++r) {
                size_t row = (size_t)bm0 + wr * 64 + mi * 16 + l4 * 4 + r;
                int col = n0 + wc * 64 + ni * 16 + l15;
                out[row * CDIM + col] = acc[mi][ni][r] + bias[ni];
            }
}

// ---------------- launch ----------------

extern "C" void kernel_launch(void* const* d_in, const int* in_sizes, int n_in,
                              void* d_out, int out_size, void* d_ws, size_t ws_size,
                              hipStream_t stream) {
    (void)n_in; (void)out_size; (void)ws_size;
    const float* x    = (const float*)d_in[0];
    const float* mask = (const float*)d_in[1];
    const float* Wqkv = (const float*)d_in[2];
    const float* bqkv = (const float*)d_in[3];
    const float* Wout = (const float*)d_in[4];
    const float* bout = (const float*)d_in[5];
    const float* rpb  = (const float*)d_in[6];
    const int*   rel  = (const int*)d_in[7];

    const int B = in_sizes[0] / (NTOK * CDIM);   // 4096
    const int M = B * NTOK;                      // 200704

    char* ws = (char*)d_ws;
    __bf16* WqkvT   = (__bf16*)(ws + OFF_WQKVT);
    __bf16* WoutT   = (__bf16*)(ws + OFF_WOUTT);
    float*  rpbF    = (float*)(ws + OFF_RPBF);
    float*  maskF   = (float*)(ws + OFF_MASKF);
    __bf16* qkvb    = (__bf16*)(ws + OFF_QKVB);
    __bf16* xb      = (__bf16*)(ws + OFF_XB);       // aliases attnout (xb dead before attn writes)
    __bf16* attnout = (__bf16*)(ws + OFF_ATTNOUT);
    float*  out     = (float*)d_out;

    prep_weights<<<(NQKV * CDIM + 255) / 256, 256, 0, stream>>>(Wqkv, Wout, WqkvT, WoutT);
    prep_frag<<<(49152 + 262144) / 256, 256, 0, stream>>>(rpb, rel, mask, rpbF, maskF);
    prep_xb<<<2048, 256, 0, stream>>>(x, xb, M * CDIM / 8);
    gemm_qkv<<<(M / 128) * (NQKV / 128), 256, 0, stream>>>(xb, WqkvT, bqkv, qkvb);
    attn<<<dim3(B, 3), 256, 0, stream>>>(qkvb, rpbF, maskF, attnout);
    out_proj<<<(M / 128) * 3, 256, 0, stream>>>(attnout, WoutT, bout, out);
}

// Round 18
// 812.857 us; speedup vs baseline: 1.2849x; 1.2849x over previous
//
#include <hip/hip_runtime.h>

#define NTOK 49
#define CDIM 384
#define HEADS 12
#define HD 32
#define NWIN 64
#define NQKV 1152
#define SCALE 0.17677669529663687f  // 32^-0.5
#define HSTR 1568                   // NTOK*HD elems per (b,h,which) block

typedef __attribute__((ext_vector_type(8))) __bf16 bf16x8;
typedef __attribute__((ext_vector_type(4))) float f32x4;

// workspace offsets (bytes), all 256-aligned
#define OFF_WQKVT   0ull                 // 1152*384 bf16 = 884736
#define OFF_WOUTT   884736ull            // 384*384 bf16  = 294912
#define OFF_RPBF    1179648ull           // 12*4*4*64*4 f32 = 196608
#define OFF_MASKF   1376256ull           // 64*4*4*64*4 f32 = 1048576
#define OFF_QKVB    8555520ull           // packed [B][12][3][49][32] bf16 = 462422016
#define OFF_ATTNOUT 470977536ull         // 200704*384 bf16 = 154140672
#define OFF_XB      OFF_ATTNOUT          // xb aliases attnout: xb dead before attn writes
// total ~625.1 MB

__device__ __forceinline__ void async_copy16(__bf16* lds_dst, const __bf16* g_src) {
    __builtin_amdgcn_global_load_lds(
        (const __attribute__((address_space(1))) void*)g_src,
        (__attribute__((address_space(3))) void*)lds_dst,
        16, 0, 0);
}

// ---------------- prep kernels ----------------

__global__ void prep_weights(const float* __restrict__ Wqkv, const float* __restrict__ Wout,
                             __bf16* __restrict__ WqkvT, __bf16* __restrict__ WoutT) {
    int idx = blockIdx.x * 256 + threadIdx.x;
    if (idx < NQKV * CDIM) {
        int n = idx / CDIM, k = idx % CDIM;
        WqkvT[idx] = (__bf16)Wqkv[(size_t)k * NQKV + n];
    }
    if (idx < CDIM * CDIM) {
        int n = idx / CDIM, k = idx % CDIM;
        WoutT[idx] = (__bf16)Wout[(size_t)k * CDIM + n];
    }
}

// fragment-layout bias tables: rpbF[h][mt][nt][lane][r], maskF[w][mt][nt][lane][r]
__global__ void prep_frag(const float* __restrict__ rpb, const int* __restrict__ rel,
                          const float* __restrict__ mask,
                          float* __restrict__ rpbF, float* __restrict__ maskF) {
    int idx = blockIdx.x * 256 + threadIdx.x;
    if (idx < 49152) {
        int r = idx & 3, lane = (idx >> 2) & 63, nt = (idx >> 8) & 3, mt = (idx >> 10) & 3, h = idx >> 12;
        int m = mt * 16 + ((lane >> 4) << 2) + r, n = nt * 16 + (lane & 15);
        rpbF[idx] = (m < NTOK && n < NTOK) ? rpb[rel[m * NTOK + n] * HEADS + h] : 0.f;
    } else {
        int i2 = idx - 49152;
        if (i2 < 262144) {
            int r = i2 & 3, lane = (i2 >> 2) & 63, nt = (i2 >> 8) & 3, mt = (i2 >> 10) & 3, w = i2 >> 12;
            int m = mt * 16 + ((lane >> 4) << 2) + r, n = nt * 16 + (lane & 15);
            maskF[i2] = (m < NTOK && n < NTOK) ? mask[(size_t)w * NTOK * NTOK + m * NTOK + n] : 0.f;
        }
    }
}

// x fp32 -> bf16, streaming (8 elems / thread / iter)
__global__ __launch_bounds__(256) void prep_xb(const float* __restrict__ x,
                                               __bf16* __restrict__ xb, int total8) {
    int stride = gridDim.x * 256;
    for (int i = blockIdx.x * 256 + threadIdx.x; i < total8; i += stride) {
        float4 a = reinterpret_cast<const float4*>(x)[i * 2];
        float4 b = reinterpret_cast<const float4*>(x)[i * 2 + 1];
        union { __bf16 h[8]; uint4 u; } t;
        t.h[0] = (__bf16)a.x; t.h[1] = (__bf16)a.y; t.h[2] = (__bf16)a.z; t.h[3] = (__bf16)a.w;
        t.h[4] = (__bf16)b.x; t.h[5] = (__bf16)b.y; t.h[6] = (__bf16)b.z; t.h[7] = (__bf16)b.w;
        reinterpret_cast<uint4*>(xb)[i] = t.u;
    }
}

// ---------------- K1: qkv GEMM, m97 structure + XCD swizzle; packed head-blocked output ----------------
// (r16-proven body; only the epilogue scatter address map changed to [b][h][3][49][32])

__global__ __launch_bounds__(256, 4) void gemm_qkv(
    const __bf16* __restrict__ xb, const __bf16* __restrict__ WqkvT,
    const float* __restrict__ bqkv, __bf16* __restrict__ qkvb)
{
    __shared__ __attribute__((aligned(16))) __bf16 smem[16384];  // A [0,8192), B [8192,16384); C overlays
    __bf16* As = smem;
    __bf16* Bs = smem + 8192;

    // bijective XCD-chunk swizzle: nwg = 14112 = 8 * 1764
    const int cpx  = 14112 >> 3;                     // 1764
    const int lid  = (blockIdx.x & 7) * cpx + (blockIdx.x >> 3);
    const int mblk = lid / 9, nblk = lid % 9;
    const int n0  = nblk * 128;
    const int bm0 = mblk * 128;

    const int tid = threadIdx.x;
    const int wave = tid >> 6, lane = tid & 63;
    const int l15 = lane & 15, l4 = lane >> 4;
    const int wr = wave >> 1, wc = wave & 1;

    f32x4 acc[4][4] = {};

    for (int k0 = 0; k0 < CDIM; k0 += 64) {
#pragma unroll
        for (int j = 0; j < 4; ++j) {
            int c = wave * 4 + j;
            int mt = c >> 1, kk = c & 1;
            const __bf16* sa = xb + (size_t)(bm0 + mt * 16 + l15) * CDIM + k0 + kk * 32 + l4 * 8;
            async_copy16(&As[c * 512], sa);
            const __bf16* sb = WqkvT + (size_t)(n0 + mt * 16 + l15) * CDIM + k0 + kk * 32 + l4 * 8;
            async_copy16(&Bs[c * 512], sb);
        }
        __syncthreads();

#pragma unroll
        for (int kk = 0; kk < 2; ++kk) {
            bf16x8 af[4], bf[4];
#pragma unroll
            for (int mi = 0; mi < 4; ++mi)
                af[mi] = *reinterpret_cast<const bf16x8*>(&As[((wr * 4 + mi) * 2 + kk) * 512 + lane * 8]);
#pragma unroll
            for (int ni = 0; ni < 4; ++ni)
                bf[ni] = *reinterpret_cast<const bf16x8*>(&Bs[((wc * 4 + ni) * 2 + kk) * 512 + lane * 8]);
#pragma unroll
            for (int mi = 0; mi < 4; ++mi)
#pragma unroll
                for (int ni = 0; ni < 4; ++ni)
                    acc[mi][ni] = __builtin_amdgcn_mfma_f32_16x16x32_bf16(af[mi], bf[ni], acc[mi][ni], 0, 0, 0);
        }
        __syncthreads();
    }

    const float scl = (n0 < CDIM) ? SCALE : 1.0f;
    float bias[4];
#pragma unroll
    for (int ni = 0; ni < 4; ++ni)
        bias[ni] = bqkv[n0 + wc * 64 + ni * 16 + l15];

    __bf16* Cs = smem;   // [128][128] bf16, byte ^= ((row>>2)&3)<<5
#pragma unroll
    for (int mi = 0; mi < 4; ++mi)
#pragma unroll
        for (int ni = 0; ni < 4; ++ni)
#pragma unroll
            for (int r = 0; r < 4; ++r) {
                int row = wr * 64 + mi * 16 + l4 * 4 + r;
                int col = wc * 64 + ni * 16 + l15;
                int byte = (row * 256 + col * 2) ^ (((row >> 2) & 3) << 5);
                *reinterpret_cast<__bf16*>(reinterpret_cast<char*>(Cs) + byte) =
                    (__bf16)((acc[mi][ni][r] + bias[ni]) * scl);
            }
    __syncthreads();

    // packed head-blocked scatter: [b][h][which][tok][d], which = n0/384, heads h0..h0+3
    const int which = n0 / CDIM;
    const int h0    = (n0 % CDIM) >> 5;
#pragma unroll
    for (int it = 0; it < 8; ++it) {
        int idx = it * 4096 + tid * 16;
        int row = idx >> 8, bcol = idx & 255;
        int sb = (row * 256 + bcol) ^ (((row >> 2) & 3) << 5);
        uint4 v = *reinterpret_cast<const uint4*>(reinterpret_cast<const char*>(Cs) + sb);
        int grow = bm0 + row;
        int b = grow / NTOK, tok = grow - b * NTOK;
        int col = bcol >> 1;                 // 0..127
        int h = h0 + (col >> 5), d = col & 31;
        *reinterpret_cast<uint4*>(
            &qkvb[(((size_t)(b * HEADS + h) * 3 + which) * NTOK + tok) * HD + d]) = v;
    }
}

// ---------------- K2: attention (r16 body; packed q/k/v base pointers) ----------------

__global__ __launch_bounds__(256) void attn(
    const __bf16* __restrict__ qkvb, const float* __restrict__ rpbF,
    const float* __restrict__ maskF, __bf16* __restrict__ attnout)
{
    __shared__ __attribute__((aligned(16))) __bf16 ps[4][2][64][8];   // [wave][kb][lane][8]
    __shared__ __attribute__((aligned(16))) __bf16 ot[64 * 136];      // [tok][head-col], stride 136
    const int b = blockIdx.x;
    const int tid = threadIdx.x;
    const int wave = tid >> 6, lane = tid & 63;
    const int l15 = lane & 15, l4 = lane >> 4;
    const int h = blockIdx.y * 4 + wave;
    const int w = b & (NWIN - 1);

    const __bf16* base = qkvb + (size_t)(b * HEADS + h) * 3 * HSTR;
    const __bf16* qb = base;
    const __bf16* kb = base + HSTR;
    const __bf16* vb = base + 2 * HSTR;
    const f32x4* rpbF4  = reinterpret_cast<const f32x4*>(rpbF);
    const f32x4* maskF4 = reinterpret_cast<const f32x4*>(maskF);

    // vT B-frags via register gather
    bf16x8 vf[2][2];
#pragma unroll
    for (int dt = 0; dt < 2; ++dt)
#pragma unroll
        for (int kb2 = 0; kb2 < 2; ++kb2)
#pragma unroll
            for (int j = 0; j < 8; ++j) {
                int tok = kb2 * 32 + l4 * 8 + j;
                vf[dt][kb2][j] = vb[(size_t)tok * HD + dt * 16 + l15];
            }

    bf16x8 kf[4];
#pragma unroll
    for (int nt = 0; nt < 4; ++nt)
        kf[nt] = *reinterpret_cast<const bf16x8*>(kb + (size_t)(nt * 16 + l15) * HD + l4 * 8);

    for (int mt = 0; mt < 4; ++mt) {
        bf16x8 qf = *reinterpret_cast<const bf16x8*>(qb + (size_t)(mt * 16 + l15) * HD + l4 * 8);

        f32x4 rb[4], mb[4];
#pragma unroll
        for (int nt = 0; nt < 4; ++nt) {
            rb[nt] = rpbF4[((h * 4 + mt) * 4 + nt) * 64 + lane];
            mb[nt] = maskF4[((w * 4 + mt) * 4 + nt) * 64 + lane];
        }

        f32x4 s[4];
#pragma unroll
        for (int nt = 0; nt < 4; ++nt) {
            f32x4 z = {};
            s[nt] = __builtin_amdgcn_mfma_f32_16x16x32_bf16(qf, kf[nt], z, 0, 0, 0);
        }

#pragma unroll
        for (int r = 0; r < 4; ++r) {
            float vals[4];
#pragma unroll
            for (int nt = 0; nt < 4; ++nt) {
                int n = nt * 16 + l15;
                vals[nt] = (n < NTOK) ? (s[nt][r] + rb[nt][r] + mb[nt][r]) : -1e30f;
            }
            float mx = fmaxf(fmaxf(vals[0], vals[1]), fmaxf(vals[2], vals[3]));
            mx = fmaxf(mx, __shfl_xor(mx, 1));
            mx = fmaxf(mx, __shfl_xor(mx, 2));
            mx = fmaxf(mx, __shfl_xor(mx, 4));
            mx = fmaxf(mx, __shfl_xor(mx, 8));
            float e0 = __expf(vals[0] - mx);
            float e1 = __expf(vals[1] - mx);
            float e2 = __expf(vals[2] - mx);
            float e3 = __expf(vals[3] - mx);
            float sum = (e0 + e1) + (e2 + e3);
            sum += __shfl_xor(sum, 1);
            sum += __shfl_xor(sum, 2);
            sum += __shfl_xor(sum, 4);
            sum += __shfl_xor(sum, 8);
            float inv = 1.0f / sum;
            float ev[4] = {e0, e1, e2, e3};
#pragma unroll
            for (int nt = 0; nt < 4; ++nt) {
                int lp = (l4 * 4 + r) + 16 * ((nt & 1) * 2 + (l15 >> 3));
                ps[wave][nt >> 1][lp][l15 & 7] = (__bf16)(ev[nt] * inv);
            }
        }

        f32x4 o[2] = {};
#pragma unroll
        for (int kb2 = 0; kb2 < 2; ++kb2) {
            bf16x8 ap = *reinterpret_cast<const bf16x8*>(&ps[wave][kb2][lane][0]);
#pragma unroll
            for (int dt = 0; dt < 2; ++dt)
                o[dt] = __builtin_amdgcn_mfma_f32_16x16x32_bf16(ap, vf[dt][kb2], o[dt], 0, 0, 0);
        }
#pragma unroll
        for (int dt = 0; dt < 2; ++dt)
#pragma unroll
            for (int r = 0; r < 4; ++r) {
                int tok = mt * 16 + l4 * 4 + r;
                ot[tok * 136 + wave * 32 + dt * 16 + l15] = (__bf16)o[dt][r];
            }
    }
    __syncthreads();

    // cooperative coalesced write: [49 rows][128 cols] -> attnout cols gy*128..+127
#pragma unroll
    for (int it = 0; it < 4; ++it) {
        int e = it * 2048 + tid * 8;
        int row = e >> 7, c2 = e & 127;
        if (row < NTOK) {
            uint4 v = *reinterpret_cast<const uint4*>(&ot[row * 136 + c2]);
            *reinterpret_cast<uint4*>(
                &attnout[((size_t)b * NTOK + row) * CDIM + blockIdx.y * 128 + c2]) = v;
        }
    }
}

// ---------------- K3: out projection, m97 structure (r16/r14-proven form) ----------------

__global__ __launch_bounds__(256, 4) void out_proj(
    const __bf16* __restrict__ A, const __bf16* __restrict__ WoutT,
    const float* __restrict__ bout, float* __restrict__ out)
{
    __shared__ __attribute__((aligned(16))) __bf16 smem[16384];  // A [0,8192), B [8192,16384)
    __bf16* As = smem;
    __bf16* Bs = smem + 8192;

    // bijective XCD-chunk swizzle: nwg = 4704 = 8 * 588; n-fastest for A-tile L2 reuse
    const int cpx  = 4704 >> 3;                      // 588
    const int lid  = (blockIdx.x & 7) * cpx + (blockIdx.x >> 3);
    const int mblk = lid / 3, nblk = lid % 3;
    const int n0  = nblk * 128;
    const int bm0 = mblk * 128;

    const int tid = threadIdx.x;
    const int wave = tid >> 6, lane = tid & 63;
    const int l15 = lane & 15, l4 = lane >> 4;
    const int wr = wave >> 1, wc = wave & 1;

    f32x4 acc[4][4] = {};

    for (int k0 = 0; k0 < CDIM; k0 += 64) {
#pragma unroll
        for (int j = 0; j < 4; ++j) {
            int c = wave * 4 + j;
            int mt = c >> 1, kk = c & 1;
            const __bf16* sa = A + (size_t)(bm0 + mt * 16 + l15) * CDIM + k0 + kk * 32 + l4 * 8;
            async_copy16(&As[c * 512], sa);
            const __bf16* sb = WoutT + (size_t)(n0 + mt * 16 + l15) * CDIM + k0 + kk * 32 + l4 * 8;
            async_copy16(&Bs[c * 512], sb);
        }
        __syncthreads();

#pragma unroll
        for (int kk = 0; kk < 2; ++kk) {
            bf16x8 af[4], bf[4];
#pragma unroll
            for (int mi = 0; mi < 4; ++mi)
                af[mi] = *reinterpret_cast<const bf16x8*>(&As[((wr * 4 + mi) * 2 + kk) * 512 + lane * 8]);
#pragma unroll
            for (int ni = 0; ni < 4; ++ni)
                bf[ni] = *reinterpret_cast<const bf16x8*>(&Bs[((wc * 4 + ni) * 2 + kk) * 512 + lane * 8]);
#pragma unroll
            for (int mi = 0; mi < 4; ++mi)
#pragma unroll
                for (int ni = 0; ni < 4; ++ni)
                    acc[mi][ni] = __builtin_amdgcn_mfma_f32_16x16x32_bf16(af[mi], bf[ni], acc[mi][ni], 0, 0, 0);
        }
        __syncthreads();
    }

    float bias[4];
#pragma unroll
    for (int ni = 0; ni < 4; ++ni)
        bias[ni] = bout[n0 + wc * 64 + ni * 16 + l15];

#pragma unroll
    for (int mi = 0; mi < 4; ++mi)
#pragma unroll
        for (int ni = 0; ni < 4; ++ni)
#pragma unroll
            for (int r = 0; r < 4; ++r) {
                size_t row = (size_t)bm0 + wr * 64 + mi * 16 + l4 * 4 + r;
                int col = n0 + wc * 64 + ni * 16 + l15;
                out[row * CDIM + col] = acc[mi][ni][r] + bias[ni];
            }
}

// ---------------- launch ----------------

extern "C" void kernel_launch(void* const* d_in, const int* in_sizes, int n_in,
                              void* d_out, int out_size, void* d_ws, size_t ws_size,
                              hipStream_t stream) {
    (void)n_in; (void)out_size; (void)ws_size;
    const float* x    = (const float*)d_in[0];
    const float* mask = (const float*)d_in[1];
    const float* Wqkv = (const float*)d_in[2];
    const float* bqkv = (const float*)d_in[3];
    const float* Wout = (const float*)d_in[4];
    const float* bout = (const float*)d_in[5];
    const float* rpb  = (const float*)d_in[6];
    const int*   rel  = (const int*)d_in[7];

    const int B = in_sizes[0] / (NTOK * CDIM);   // 4096
    const int M = B * NTOK;                      // 200704

    char* ws = (char*)d_ws;
    __bf16* WqkvT   = (__bf16*)(ws + OFF_WQKVT);
    __bf16* WoutT   = (__bf16*)(ws + OFF_WOUTT);
    float*  rpbF    = (float*)(ws + OFF_RPBF);
    float*  maskF   = (float*)(ws + OFF_MASKF);
    __bf16* qkvb    = (__bf16*)(ws + OFF_QKVB);
    __bf16* xb      = (__bf16*)(ws + OFF_XB);       // aliases attnout (xb dead before attn writes)
    __bf16* attnout = (__bf16*)(ws + OFF_ATTNOUT);
    float*  out     = (float*)d_out;

    prep_weights<<<(NQKV * CDIM + 255) / 256, 256, 0, stream>>>(Wqkv, Wout, WqkvT, WoutT);
    prep_frag<<<(49152 + 262144) / 256, 256, 0, stream>>>(rpb, rel, mask, rpbF, maskF);
    prep_xb<<<2048, 256, 0, stream>>>(x, xb, M * CDIM / 8);
    gemm_qkv<<<(M / 128) * (NQKV / 128), 256, 0, stream>>>(xb, WqkvT, bqkv, qkvb);
    attn<<<dim3(B, 3), 256, 0, stream>>>(qkvb, rpbF, maskF, attnout);
    out_proj<<<(M / 128) * 3, 256, 0, stream>>>(attnout, WoutT, bout, out);
}